// Round 1
// baseline (11531.857 us; speedup 1.0000x reference)
//
#include <hip/hip_runtime.h>
#include <math.h>

#define N_NODES 100000
#define DIM 128
#define NREL 4
#define NEDGE 1600000
#define LN_EPS 1e-3f

// ---------------------------------------------------------------------------
// Prep: per-relation fused bias  bfr[r][d] = b_fuse[d] + sum_k rel[r][k]*W_fuse[D+k][d]
// and softmax of rel_weights.
// ---------------------------------------------------------------------------
__global__ __launch_bounds__(512) void prep_kernel(
    const float* __restrict__ rel_emb,     // [R][D]
    const float* __restrict__ W_fuse,      // [2D][D]
    const float* __restrict__ b_fuse,      // [D]
    const float* __restrict__ rel_weights, // [R]
    float* __restrict__ bfr,               // [R][D] out
    float* __restrict__ wsm)               // [R] out
{
    int t = threadIdx.x;      // 0..511
    int r = t >> 7;           // 0..3
    int d = t & 127;
    float acc = b_fuse[d];
    for (int k = 0; k < DIM; ++k)
        acc += rel_emb[r * DIM + k] * W_fuse[(DIM + k) * DIM + d];
    bfr[r * DIM + d] = acc;
    if (t < NREL) {
        float m = rel_weights[0];
        for (int i = 1; i < NREL; ++i) m = fmaxf(m, rel_weights[i]);
        float s = 0.f;
        for (int i = 0; i < NREL; ++i) s += expf(rel_weights[i] - m);
        wsm[t] = expf(rel_weights[t] - m) / s;
    }
}

// ---------------------------------------------------------------------------
// Scatter: msg[rows[e]] += vals[e] * X[cols[e]]  (one relation).
// 32 lanes per edge, float4 per lane, hardware fp32 atomics.
// ---------------------------------------------------------------------------
__global__ __launch_bounds__(256) void scatter_kernel(
    const float* __restrict__ X,
    const int* __restrict__ rows,
    const int* __restrict__ cols,
    const float* __restrict__ vals,
    float* __restrict__ msg)
{
    int t = threadIdx.x;
    int e = blockIdx.x * 8 + (t >> 5);   // 8 edges per 256-thread block
    int lane = t & 31;                   // 32 lanes x float4 = 128 floats
    int row = rows[e];
    int col = cols[e];
    float v = vals[e];
    const float4* xs = (const float4*)(X + (size_t)col * DIM);
    float4 x = xs[lane];
    float* dst = msg + (size_t)row * DIM + lane * 4;
    unsafeAtomicAdd(dst + 0, v * x.x);
    unsafeAtomicAdd(dst + 1, v * x.y);
    unsafeAtomicAdd(dst + 2, v * x.z);
    unsafeAtomicAdd(dst + 3, v * x.w);
}

// ---------------------------------------------------------------------------
// Dense per-relation: comb (+)= w[r] * (relu(msg@W1 + bfr) @ W2 + brel)
// 32 rows per 256-thread block; thread (half,c) holds 16 rows of column c.
// Both 128x128 GEMMs fused; intermediate T kept in LDS.
// ---------------------------------------------------------------------------
__global__ __launch_bounds__(256) void dense_kernel(
    const float* __restrict__ msg,
    const float* __restrict__ W1,     // W_fuse[0:D][:]
    const float* __restrict__ bfr_r,  // [D]
    const float* __restrict__ W2,     // W_rel[r]
    const float* __restrict__ brel_r, // [D]
    const float* __restrict__ wsm,    // [R]
    int r, int accumulate,
    float* __restrict__ comb)
{
    __shared__ float sIn[32][DIM];
    __shared__ float sT[32][DIM];
    int t = threadIdx.x;
    int c = t & 127;
    int half = t >> 7;          // 0 or 1 -> rows [0,16) or [16,32)
    int row0 = blockIdx.x * 32;

    // stage 32x128 msg tile (coalesced float4)
    {
        const float4* src = (const float4*)(msg + (size_t)row0 * DIM);
        float4* dst = (float4*)(&sIn[0][0]);
        for (int i = t; i < 32 * DIM / 4; i += 256) dst[i] = src[i];
    }
    __syncthreads();

    float acc[16];
#pragma unroll
    for (int i = 0; i < 16; ++i) acc[i] = 0.f;
    for (int k = 0; k < DIM; ++k) {
        float w1 = W1[k * DIM + c];           // coalesced, L1/L2-resident
#pragma unroll
        for (int rr = 0; rr < 16; ++rr)
            acc[rr] += sIn[half * 16 + rr][k] * w1;  // LDS broadcast
    }
    float bv = bfr_r[c];
#pragma unroll
    for (int rr = 0; rr < 16; ++rr)
        sT[half * 16 + rr][c] = fmaxf(acc[rr] + bv, 0.f);
    __syncthreads();

    float acc2[16];
#pragma unroll
    for (int i = 0; i < 16; ++i) acc2[i] = 0.f;
    for (int k = 0; k < DIM; ++k) {
        float w2 = W2[k * DIM + c];
#pragma unroll
        for (int rr = 0; rr < 16; ++rr)
            acc2[rr] += sT[half * 16 + rr][k] * w2;
    }
    float wr = wsm[r];
    float bb = brel_r[c];
#pragma unroll
    for (int rr = 0; rr < 16; ++rr) {
        size_t gi = (size_t)(row0 + half * 16 + rr) * DIM + c;
        float val = wr * (acc2[rr] + bb);
        comb[gi] = accumulate ? (comb[gi] + val) : val;
    }
}

// ---------------------------------------------------------------------------
// Final: out = LN(X + sigmoid(X@Wg + bg) * comb).  comb may alias out
// (block-local in-place: all comb reads happen before any out writes,
// separated by barriers; rows are block-exclusive).
// ---------------------------------------------------------------------------
__global__ __launch_bounds__(256) void final_kernel(
    const float* __restrict__ X,
    const float* __restrict__ comb,
    const float* __restrict__ Wg,
    const float* __restrict__ bg,
    const float* __restrict__ gamma,
    const float* __restrict__ beta,
    float* __restrict__ out)
{
    __shared__ float sX[32][DIM];
    __shared__ float red[32][8];
    __shared__ float red2[32][8];
    __shared__ float smu[32], srs[32];
    int t = threadIdx.x;
    int c = t & 127;
    int half = t >> 7;
    int row0 = blockIdx.x * 32;

    {
        const float4* src = (const float4*)(X + (size_t)row0 * DIM);
        float4* dst = (float4*)(&sX[0][0]);
        for (int i = t; i < 32 * DIM / 4; i += 256) dst[i] = src[i];
    }
    __syncthreads();

    float acc[16];
#pragma unroll
    for (int i = 0; i < 16; ++i) acc[i] = 0.f;
    for (int k = 0; k < DIM; ++k) {
        float wg = Wg[k * DIM + c];
#pragma unroll
        for (int rr = 0; rr < 16; ++rr)
            acc[rr] += sX[half * 16 + rr][k] * wg;
    }
    float bgv = bg[c];
    float xv[16];
#pragma unroll
    for (int rr = 0; rr < 16; ++rr) {
        int row = half * 16 + rr;
        float g = 1.f / (1.f + expf(-(acc[rr] + bgv)));
        float cb = comb[(size_t)(row0 + row) * DIM + c];
        xv[rr] = sX[row][c] + g * cb;
    }
    __syncthreads();   // all sX/comb reads done
#pragma unroll
    for (int rr = 0; rr < 16; ++rr)
        sX[half * 16 + rr][c] = xv[rr];
    __syncthreads();

    // LayerNorm reduction: 8 threads per row, 16 cols each
    int row = t >> 3;
    int seg = t & 7;
    float s = 0.f, s2 = 0.f;
#pragma unroll
    for (int i = 0; i < 16; ++i) {
        float v = sX[row][seg * 16 + i];
        s += v;
        s2 += v * v;
    }
    red[row][seg] = s;
    red2[row][seg] = s2;
    __syncthreads();
    if (seg == 0) {
        float ts = 0.f, ts2 = 0.f;
#pragma unroll
        for (int i = 0; i < 8; ++i) { ts += red[row][i]; ts2 += red2[row][i]; }
        float mu = ts / DIM;
        float var = ts2 / DIM - mu * mu;
        smu[row] = mu;
        srs[row] = rsqrtf(var + LN_EPS);
    }
    __syncthreads();
    float gm = gamma[c], bt = beta[c];
#pragma unroll
    for (int rr = 0; rr < 16; ++rr) {
        int rw = half * 16 + rr;
        float v = (sX[rw][c] - smu[rw]) * srs[rw];
        out[(size_t)(row0 + rw) * DIM + c] = v * gm + bt;
    }
}

// ---------------------------------------------------------------------------
extern "C" void kernel_launch(void* const* d_in, const int* in_sizes, int n_in,
                              void* d_out, int out_size, void* d_ws, size_t ws_size,
                              hipStream_t stream) {
    const float* X     = (const float*)d_in[0];
    const float* rel   = (const float*)d_in[1];
    const int*   arows = (const int*)d_in[2];
    const int*   acols = (const int*)d_in[3];
    const float* avals = (const float*)d_in[4];
    const float* Wf    = (const float*)d_in[5];
    const float* bf    = (const float*)d_in[6];
    const float* Wr    = (const float*)d_in[7];
    const float* br    = (const float*)d_in[8];
    const float* rw    = (const float*)d_in[9];
    const float* Wg    = (const float*)d_in[10];
    const float* bg    = (const float*)d_in[11];
    const float* gamma = (const float*)d_in[12];
    const float* beta  = (const float*)d_in[13];
    float* out = (float*)d_out;

    const size_t ND = (size_t)N_NODES * DIM;
    // workspace: msg[N*D] + bfr[R*D] + wsm[R]   (~51.2 MB)
    float* msg = (float*)d_ws;
    float* bfr = msg + ND;
    float* wsm = bfr + NREL * DIM;
    // comb lives in d_out (safe: fully written at r=0, final kernel is
    // block-local in-place)
    float* comb = out;

    prep_kernel<<<1, 512, 0, stream>>>(rel, Wf, bf, rw, bfr, wsm);

    for (int r = 0; r < NREL; ++r) {
        hipMemsetAsync(msg, 0, ND * sizeof(float), stream);
        scatter_kernel<<<NEDGE / 8, 256, 0, stream>>>(
            X, arows + (size_t)r * NEDGE, acols + (size_t)r * NEDGE,
            avals + (size_t)r * NEDGE, msg);
        dense_kernel<<<N_NODES / 32, 256, 0, stream>>>(
            msg, Wf, bfr + r * DIM, Wr + (size_t)r * DIM * DIM, br + r * DIM,
            wsm, r, r > 0 ? 1 : 0, comb);
    }

    final_kernel<<<N_NODES / 32, 256, 0, stream>>>(X, comb, Wg, bg, gamma,
                                                   beta, out);
}

// Round 2
// 1900.175 us; speedup vs baseline: 6.0688x; 6.0688x over previous
//
#include <hip/hip_runtime.h>
#include <math.h>

#define N_NODES 100000
#define DIM 128
#define NREL 4
#define NEDGE 1600000
#define LN_EPS 1e-3f
#define SCAN_CHUNK 1024
#define NCHUNKS ((N_NODES + SCAN_CHUNK - 1) / SCAN_CHUNK)   // 98

// ---------------------------------------------------------------------------
// Prep: bfr[r][d] = b_fuse[d] + sum_k rel[r][k]*W_fuse[D+k][d]; softmax(rel_w)
// ---------------------------------------------------------------------------
__global__ __launch_bounds__(512) void prep_kernel(
    const float* __restrict__ rel_emb,
    const float* __restrict__ W_fuse,
    const float* __restrict__ b_fuse,
    const float* __restrict__ rel_weights,
    float* __restrict__ bfr,
    float* __restrict__ wsm)
{
    int t = threadIdx.x;
    int r = t >> 7;
    int d = t & 127;
    float acc = b_fuse[d];
    for (int k = 0; k < DIM; ++k)
        acc += rel_emb[r * DIM + k] * W_fuse[(DIM + k) * DIM + d];
    bfr[r * DIM + d] = acc;
    if (t < NREL) {
        float m = rel_weights[0];
        for (int i = 1; i < NREL; ++i) m = fmaxf(m, rel_weights[i]);
        float s = 0.f;
        for (int i = 0; i < NREL; ++i) s += expf(rel_weights[i] - m);
        wsm[t] = expf(rel_weights[t] - m) / s;
    }
}

// ---------------------------------------------------------------------------
// CSR build, step 1: histogram of destination rows (int atomics, L2-resident)
// ---------------------------------------------------------------------------
__global__ __launch_bounds__(256) void hist_kernel(
    const int* __restrict__ rows, int* __restrict__ counts)
{
    int tid = blockIdx.x * 256 + threadIdx.x;
    if (tid < NEDGE) atomicAdd(&counts[rows[tid]], 1);
}

// ---------------------------------------------------------------------------
// CSR build, step 2a: per-chunk exclusive scan (chunk = 1024 elems / block)
// ---------------------------------------------------------------------------
__global__ __launch_bounds__(256) void scan1_kernel(
    const int* __restrict__ counts, int* __restrict__ row_ptr,
    int* __restrict__ chunksums)
{
    __shared__ int s[256];
    int chunk = blockIdx.x;
    int t = threadIdx.x;
    int base = chunk * SCAN_CHUNK + t * 4;
    int v0 = (base + 0 < N_NODES) ? counts[base + 0] : 0;
    int v1 = (base + 1 < N_NODES) ? counts[base + 1] : 0;
    int v2 = (base + 2 < N_NODES) ? counts[base + 2] : 0;
    int v3 = (base + 3 < N_NODES) ? counts[base + 3] : 0;
    int p1 = v0, p2 = v0 + v1, p3 = v0 + v1 + v2, tsum = p3 + v3;
    int run = tsum;
    s[t] = run;
    __syncthreads();
    for (int off = 1; off < 256; off <<= 1) {
        int other = (t >= off) ? s[t - off] : 0;
        __syncthreads();
        run += other;
        s[t] = run;
        __syncthreads();
    }
    int excl = run - tsum;   // exclusive offset within chunk
    if (t == 255) chunksums[chunk] = run;
    if (base + 0 < N_NODES) row_ptr[base + 0] = excl;
    if (base + 1 < N_NODES) row_ptr[base + 1] = excl + p1;
    if (base + 2 < N_NODES) row_ptr[base + 2] = excl + p2;
    if (base + 3 < N_NODES) row_ptr[base + 3] = excl + p3;
}

// step 2b: exclusive scan of the 98 chunk sums (in place)
__global__ __launch_bounds__(128) void scan2_kernel(int* __restrict__ chunksums)
{
    __shared__ int s[128];
    int t = threadIdx.x;
    int v = (t < NCHUNKS) ? chunksums[t] : 0;
    int run = v;
    s[t] = run;
    __syncthreads();
    for (int off = 1; off < 128; off <<= 1) {
        int other = (t >= off) ? s[t - off] : 0;
        __syncthreads();
        run += other;
        s[t] = run;
        __syncthreads();
    }
    if (t < NCHUNKS) chunksums[t] = run - v;
}

// step 2c: add chunk offsets; emit row_ptr and a mutable cursor copy
__global__ __launch_bounds__(256) void scan3_kernel(
    int* __restrict__ row_ptr, const int* __restrict__ chunksums,
    int* __restrict__ cursor)
{
    int chunk = blockIdx.x;
    int off = chunksums[chunk];
    int base = chunk * SCAN_CHUNK + threadIdx.x * 4;
#pragma unroll
    for (int i = 0; i < 4; ++i) {
        int idx = base + i;
        if (idx < N_NODES) {
            int p = row_ptr[idx] + off;
            row_ptr[idx] = p;
            cursor[idx] = p;
        }
    }
    if (chunk == 0 && threadIdx.x == 0) row_ptr[N_NODES] = NEDGE;
}

// ---------------------------------------------------------------------------
// CSR build, step 3: bucket edges by row. (col, val) packed into int2.
// ---------------------------------------------------------------------------
__global__ __launch_bounds__(256) void reorder_kernel(
    const int* __restrict__ rows, const int* __restrict__ cols,
    const float* __restrict__ vals, int* __restrict__ cursor,
    int2* __restrict__ edges)
{
    int tid = blockIdx.x * 256 + threadIdx.x;
    if (tid < NEDGE) {
        int row = rows[tid];
        int pos = atomicAdd(&cursor[row], 1);
        edges[pos] = make_int2(cols[tid], __float_as_int(vals[tid]));
    }
}

// ---------------------------------------------------------------------------
// Fused per-relation: segment-sum gather (32 nodes) -> LDS -> two 128x128
// GEMMs -> comb (+)= w[r]*(relu(msg@W1+bfr)@W2+brel)
// ---------------------------------------------------------------------------
__global__ __launch_bounds__(256) void fused_dense_kernel(
    const float* __restrict__ X,
    const int* __restrict__ row_ptr,
    const int2* __restrict__ edges,
    const float* __restrict__ W1,
    const float* __restrict__ bfr_r,
    const float* __restrict__ W2,
    const float* __restrict__ brel_r,
    const float* __restrict__ wsm,
    int r, int accumulate,
    float* __restrict__ comb)
{
    __shared__ float sIn[32][DIM];
    __shared__ float sT[32][DIM];
    int t = threadIdx.x;
    int row0 = blockIdx.x * 32;

    // ---- Phase A: gather-side segment sum, 32-lane group x float4 = 128 f
    int grp = t >> 5, lane = t & 31;
    for (int i = 0; i < 4; ++i) {
        int ln = grp * 4 + i;
        int node = row0 + ln;
        int s = row_ptr[node], e = row_ptr[node + 1];
        float4 acc = make_float4(0.f, 0.f, 0.f, 0.f);
        int ee = s;
        if (ee < e) {
            int2 cv = edges[ee];           // prefetched edge
            for (;;) {
                int2 cur = cv;
                ++ee;
                if (ee < e) cv = edges[ee];
                float v = __int_as_float(cur.y);
                const float4* xr = (const float4*)(X + (size_t)cur.x * DIM);
                float4 x = xr[lane];
                acc.x += v * x.x; acc.y += v * x.y;
                acc.z += v * x.z; acc.w += v * x.w;
                if (ee >= e) break;
            }
        }
        ((float4*)&sIn[ln][0])[lane] = acc;
    }
    __syncthreads();

    // ---- Phase B: fused(msg) = relu(msg@W1 + bfr)
    int c = t & 127;
    int half = t >> 7;
    float acc[16];
#pragma unroll
    for (int i = 0; i < 16; ++i) acc[i] = 0.f;
    for (int k = 0; k < DIM; ++k) {
        float w1 = W1[k * DIM + c];
#pragma unroll
        for (int rr = 0; rr < 16; ++rr)
            acc[rr] += sIn[half * 16 + rr][k] * w1;
    }
    float bv = bfr_r[c];
#pragma unroll
    for (int rr = 0; rr < 16; ++rr)
        sT[half * 16 + rr][c] = fmaxf(acc[rr] + bv, 0.f);
    __syncthreads();

    // ---- Phase C: out = fused @ W2 + brel, weighted accumulate
    float acc2[16];
#pragma unroll
    for (int i = 0; i < 16; ++i) acc2[i] = 0.f;
    for (int k = 0; k < DIM; ++k) {
        float w2 = W2[k * DIM + c];
#pragma unroll
        for (int rr = 0; rr < 16; ++rr)
            acc2[rr] += sT[half * 16 + rr][k] * w2;
    }
    float wr = wsm[r];
    float bb = brel_r[c];
#pragma unroll
    for (int rr = 0; rr < 16; ++rr) {
        size_t gi = (size_t)(row0 + half * 16 + rr) * DIM + c;
        float val = wr * (acc2[rr] + bb);
        comb[gi] = accumulate ? (comb[gi] + val) : val;
    }
}

// ---------------------------------------------------------------------------
// Final: out = LN(X + sigmoid(X@Wg + bg) * comb); comb aliases out (safe:
// block-local in-place, barrier-separated).
// ---------------------------------------------------------------------------
__global__ __launch_bounds__(256) void final_kernel(
    const float* __restrict__ X,
    const float* __restrict__ comb,
    const float* __restrict__ Wg,
    const float* __restrict__ bg,
    const float* __restrict__ gamma,
    const float* __restrict__ beta,
    float* __restrict__ out)
{
    __shared__ float sX[32][DIM];
    __shared__ float red[32][8];
    __shared__ float red2[32][8];
    __shared__ float smu[32], srs[32];
    int t = threadIdx.x;
    int c = t & 127;
    int half = t >> 7;
    int row0 = blockIdx.x * 32;

    {
        const float4* src = (const float4*)(X + (size_t)row0 * DIM);
        float4* dst = (float4*)(&sX[0][0]);
        for (int i = t; i < 32 * DIM / 4; i += 256) dst[i] = src[i];
    }
    __syncthreads();

    float acc[16];
#pragma unroll
    for (int i = 0; i < 16; ++i) acc[i] = 0.f;
    for (int k = 0; k < DIM; ++k) {
        float wg = Wg[k * DIM + c];
#pragma unroll
        for (int rr = 0; rr < 16; ++rr)
            acc[rr] += sX[half * 16 + rr][k] * wg;
    }
    float bgv = bg[c];
    float xv[16];
#pragma unroll
    for (int rr = 0; rr < 16; ++rr) {
        int row = half * 16 + rr;
        float g = 1.f / (1.f + expf(-(acc[rr] + bgv)));
        float cb = comb[(size_t)(row0 + row) * DIM + c];
        xv[rr] = sX[row][c] + g * cb;
    }
    __syncthreads();
#pragma unroll
    for (int rr = 0; rr < 16; ++rr)
        sX[half * 16 + rr][c] = xv[rr];
    __syncthreads();

    int row = t >> 3;
    int seg = t & 7;
    float s = 0.f, s2 = 0.f;
#pragma unroll
    for (int i = 0; i < 16; ++i) {
        float v = sX[row][seg * 16 + i];
        s += v;
        s2 += v * v;
    }
    red[row][seg] = s;
    red2[row][seg] = s2;
    __syncthreads();
    if (seg == 0) {
        float ts = 0.f, ts2 = 0.f;
#pragma unroll
        for (int i = 0; i < 8; ++i) { ts += red[row][i]; ts2 += red2[row][i]; }
        float mu = ts / DIM;
        float var = ts2 / DIM - mu * mu;
        smu[row] = mu;
        srs[row] = rsqrtf(var + LN_EPS);
    }
    __syncthreads();
    float gm = gamma[c], bt = beta[c];
#pragma unroll
    for (int rr = 0; rr < 16; ++rr) {
        int rw = half * 16 + rr;
        float v = (sX[rw][c] - smu[rw]) * srs[rw];
        out[(size_t)(row0 + rw) * DIM + c] = v * gm + bt;
    }
}

// ---------------------------------------------------------------------------
extern "C" void kernel_launch(void* const* d_in, const int* in_sizes, int n_in,
                              void* d_out, int out_size, void* d_ws, size_t ws_size,
                              hipStream_t stream) {
    const float* X     = (const float*)d_in[0];
    const float* rel   = (const float*)d_in[1];
    const int*   arows = (const int*)d_in[2];
    const int*   acols = (const int*)d_in[3];
    const float* avals = (const float*)d_in[4];
    const float* Wf    = (const float*)d_in[5];
    const float* bf    = (const float*)d_in[6];
    const float* Wr    = (const float*)d_in[7];
    const float* br    = (const float*)d_in[8];
    const float* rw    = (const float*)d_in[9];
    const float* Wg    = (const float*)d_in[10];
    const float* bg    = (const float*)d_in[11];
    const float* gamma = (const float*)d_in[12];
    const float* beta  = (const float*)d_in[13];
    float* out = (float*)d_out;

    // workspace layout (edges first for 8B alignment): ~14 MB total
    int2*  edges     = (int2*)d_ws;                       // E int2
    float* bfr       = (float*)(edges + NEDGE);           // R*D
    float* wsm       = bfr + NREL * DIM;                  // R
    int*   counts    = (int*)(wsm + NREL);                // N
    int*   row_ptr   = counts + N_NODES;                  // N+1
    int*   cursor    = row_ptr + N_NODES + 1;             // N
    int*   chunksums = cursor + N_NODES;                  // 128
    float* comb      = out;   // accumulate into d_out; final_kernel is in-place

    prep_kernel<<<1, 512, 0, stream>>>(rel, Wf, bf, rw, bfr, wsm);

    const int EB = (NEDGE + 255) / 256;   // 6250
    for (int r = 0; r < NREL; ++r) {
        const int* rows_r = arows + (size_t)r * NEDGE;
        hipMemsetAsync(counts, 0, N_NODES * sizeof(int), stream);
        hist_kernel<<<EB, 256, 0, stream>>>(rows_r, counts);
        scan1_kernel<<<NCHUNKS, 256, 0, stream>>>(counts, row_ptr, chunksums);
        scan2_kernel<<<1, 128, 0, stream>>>(chunksums);
        scan3_kernel<<<NCHUNKS, 256, 0, stream>>>(row_ptr, chunksums, cursor);
        reorder_kernel<<<EB, 256, 0, stream>>>(
            rows_r, acols + (size_t)r * NEDGE, avals + (size_t)r * NEDGE,
            cursor, edges);
        fused_dense_kernel<<<N_NODES / 32, 256, 0, stream>>>(
            X, row_ptr, edges, Wf, bfr + r * DIM,
            Wr + (size_t)r * DIM * DIM, br + r * DIM,
            wsm, r, r > 0 ? 1 : 0, comb);
    }

    final_kernel<<<(N_NODES + 31) / 32, 256, 0, stream>>>(
        X, comb, Wg, bg, gamma, beta, out);
}

// Round 3
// 1898.976 us; speedup vs baseline: 6.0727x; 1.0006x over previous
//
#include <hip/hip_runtime.h>
#include <math.h>
#include <stdint.h>

#define N_NODES 100000
#define DIM 128
#define NREL 4
#define NEDGE 1600000
#define LN_EPS 1e-3f

__device__ __forceinline__ float bf2f(unsigned short b) {
    return __uint_as_float(((unsigned int)b) << 16);
}
__device__ __forceinline__ unsigned short f2bf(float f) {
    unsigned int u = __float_as_uint(f);
    u += 0x7FFFu + ((u >> 16) & 1u);      // RN-even
    return (unsigned short)(u >> 16);
}

// ---------------------------------------------------------------------------
// Prep: bfr[r][d] = b_fuse[d] + sum_k rel[r][k]*W_fuse[D+k][d]; softmax(rel_w)
// ---------------------------------------------------------------------------
__global__ __launch_bounds__(512) void prep_kernel(
    const float* __restrict__ rel_emb, const float* __restrict__ W_fuse,
    const float* __restrict__ b_fuse, const float* __restrict__ rel_weights,
    float* __restrict__ bfr, float* __restrict__ wsm)
{
    int t = threadIdx.x;
    int r = t >> 7;
    int d = t & 127;
    float acc = b_fuse[d];
    for (int k = 0; k < DIM; ++k)
        acc += rel_emb[r * DIM + k] * W_fuse[(DIM + k) * DIM + d];
    bfr[r * DIM + d] = acc;
    if (t < NREL) {
        float m = rel_weights[0];
        for (int i = 1; i < NREL; ++i) m = fmaxf(m, rel_weights[i]);
        float s = 0.f;
        for (int i = 0; i < NREL; ++i) s += expf(rel_weights[i] - m);
        wsm[t] = expf(rel_weights[t] - m) / s;
    }
}

// ---------------------------------------------------------------------------
// X (fp32) -> Xb (bf16), halves gather traffic. 3.2M threads x float4.
// ---------------------------------------------------------------------------
__global__ __launch_bounds__(256) void xb_kernel(
    const float* __restrict__ X, unsigned short* __restrict__ Xb)
{
    int idx = blockIdx.x * 256 + threadIdx.x;   // N*DIM/4 = 3.2M exact
    float4 f = ((const float4*)X)[idx];
    ushort4 o;
    o.x = f2bf(f.x); o.y = f2bf(f.y); o.z = f2bf(f.z); o.w = f2bf(f.w);
    ((ushort4*)Xb)[idx] = o;
}

// ---------------------------------------------------------------------------
// CSR build over a group of relations (grid.y = relation within group)
// ---------------------------------------------------------------------------
__global__ __launch_bounds__(256) void hist_kernel(
    const int* __restrict__ arows, int r0, int* __restrict__ counts)
{
    int e = blockIdx.x * 256 + threadIdx.x;
    int rl = blockIdx.y;
    if (e < NEDGE) {
        int row = arows[(size_t)(r0 + rl) * NEDGE + e];
        atomicAdd(&counts[rl * N_NODES + row], 1);
    }
}

// in-place per-chunk exclusive scan (1024 elems/block)
__global__ __launch_bounds__(256) void scan1_kernel(
    int* __restrict__ counts, int* __restrict__ chunksums, int M)
{
    __shared__ int s[256];
    int chunk = blockIdx.x, t = threadIdx.x;
    int base = chunk * 1024 + t * 4;
    int v0 = (base + 0 < M) ? counts[base + 0] : 0;
    int v1 = (base + 1 < M) ? counts[base + 1] : 0;
    int v2 = (base + 2 < M) ? counts[base + 2] : 0;
    int v3 = (base + 3 < M) ? counts[base + 3] : 0;
    int p1 = v0, p2 = v0 + v1, p3 = v0 + v1 + v2, tsum = p3 + v3;
    int run = tsum;
    s[t] = run;
    __syncthreads();
    for (int off = 1; off < 256; off <<= 1) {
        int other = (t >= off) ? s[t - off] : 0;
        __syncthreads();
        run += other;
        s[t] = run;
        __syncthreads();
    }
    int excl = run - tsum;
    if (t == 255) chunksums[chunk] = run;
    if (base + 0 < M) counts[base + 0] = excl;
    if (base + 1 < M) counts[base + 1] = excl + p1;
    if (base + 2 < M) counts[base + 2] = excl + p2;
    if (base + 3 < M) counts[base + 3] = excl + p3;
}

__global__ __launch_bounds__(512) void scan2_kernel(
    int* __restrict__ chunksums, int nchunks)
{
    __shared__ int s[512];
    int t = threadIdx.x;
    int v = (t < nchunks) ? chunksums[t] : 0;
    int run = v;
    s[t] = run;
    __syncthreads();
    for (int off = 1; off < 512; off <<= 1) {
        int other = (t >= off) ? s[t - off] : 0;
        __syncthreads();
        run += other;
        s[t] = run;
        __syncthreads();
    }
    if (t < nchunks) chunksums[t] = run - v;
}

__global__ __launch_bounds__(256) void scan3_kernel(
    int* __restrict__ counts, const int* __restrict__ chunksums, int M)
{
    int chunk = blockIdx.x;
    int off = chunksums[chunk];
    int base = chunk * 1024 + threadIdx.x * 4;
#pragma unroll
    for (int i = 0; i < 4; ++i)
        if (base + i < M) counts[base + i] += off;
}

// bucket edges; packs (col:17b | val:15b sign-free bf16) into 4 bytes.
// counts (=cursor) is mutated into a segment-END array.
__global__ __launch_bounds__(256) void reorder_kernel(
    const int* __restrict__ arows, const int* __restrict__ acols,
    const float* __restrict__ avals, int r0,
    int* __restrict__ cursor, unsigned int* __restrict__ edges)
{
    int e = blockIdx.x * 256 + threadIdx.x;
    int rl = blockIdx.y;
    if (e < NEDGE) {
        size_t off = (size_t)(r0 + rl) * NEDGE + e;
        int row = arows[off];
        int pos = atomicAdd(&cursor[rl * N_NODES + row], 1);
        unsigned int vb = __float_as_uint(avals[off]);
        vb += 0x7FFFu + ((vb >> 16) & 1u);         // RN-even to bf16
        edges[pos] = ((unsigned int)acols[off] << 15) | ((vb >> 16) & 0x7FFFu);
    }
}

// ---------------------------------------------------------------------------
// Mega kernel: per 32-row tile, for each relation in group:
//   gather(bf16 X) -> GEMM1(relu) -> GEMM2, comb accumulated in registers.
// Last group also fuses gate GEMM + residual + LayerNorm epilogue.
// One 16KB LDS tile reused throughout (occupancy ~8 blocks/CU).
// Mapping: wave w (t>>6) owns rows [8w,8w+8); lane l owns cols l and l+64.
// ---------------------------------------------------------------------------
__global__ __launch_bounds__(256) void mega_kernel(
    const unsigned short* __restrict__ Xb,
    const float* __restrict__ X,
    const int* __restrict__ segend,        // size nr*N: end offsets
    const unsigned int* __restrict__ edges,
    const float* __restrict__ W1,
    const float* __restrict__ bfr,
    const float* __restrict__ Wr,
    const float* __restrict__ br,
    const float* __restrict__ wsm,
    int r0, int nr, int accumulate, int do_final,
    const float* __restrict__ Wg,
    const float* __restrict__ bg,
    const float* __restrict__ gamma,
    const float* __restrict__ beta,
    float* __restrict__ comb,              // aliases out
    float* __restrict__ out)
{
    __shared__ float sIn[32][DIM];
    __shared__ float red[32][8], red2[32][8];
    __shared__ float smu[32], srs[32];

    int t = threadIdx.x;
    int row0 = blockIdx.x * 32;
    int w = t >> 6;            // wave 0..3
    int l = t & 63;
    int grp = t >> 5, lane = t & 31;   // gather: 8 groups x 32 lanes

    float comb_acc[8][2];
#pragma unroll
    for (int rr = 0; rr < 8; ++rr) {
        if (accumulate) {
            size_t gi = (size_t)(row0 + w * 8 + rr) * DIM + l;
            comb_acc[rr][0] = comb[gi];
            comb_acc[rr][1] = comb[gi + 64];
        } else {
            comb_acc[rr][0] = 0.f;
            comb_acc[rr][1] = 0.f;
        }
    }

    for (int rl = 0; rl < nr; ++rl) {
        int r = r0 + rl;
        __syncthreads();   // sIn free (prev iter / init)

        // ---- Phase A: segment-sum gather (bf16 X, packed edges)
#pragma unroll
        for (int i = 0; i < 4; ++i) {
            int ln = grp * 4 + i;
            int g = rl * N_NODES + row0 + ln;
            int s = (g == 0) ? 0 : segend[g - 1];
            int e = segend[g];
            float4 a0 = make_float4(0.f, 0.f, 0.f, 0.f);
            float4 a1 = make_float4(0.f, 0.f, 0.f, 0.f);
            int ee = s;
            for (; ee + 1 < e; ee += 2) {     // 2 X-loads in flight
                unsigned int p0 = edges[ee], p1 = edges[ee + 1];
                const ushort4* x0 =
                    (const ushort4*)(Xb + ((size_t)(p0 >> 15) << 7));
                const ushort4* x1 =
                    (const ushort4*)(Xb + ((size_t)(p1 >> 15) << 7));
                ushort4 q0 = x0[lane];
                ushort4 q1 = x1[lane];
                float v0 = __uint_as_float((p0 & 0x7FFFu) << 16);
                float v1 = __uint_as_float((p1 & 0x7FFFu) << 16);
                a0.x += v0 * bf2f(q0.x); a0.y += v0 * bf2f(q0.y);
                a0.z += v0 * bf2f(q0.z); a0.w += v0 * bf2f(q0.w);
                a1.x += v1 * bf2f(q1.x); a1.y += v1 * bf2f(q1.y);
                a1.z += v1 * bf2f(q1.z); a1.w += v1 * bf2f(q1.w);
            }
            if (ee < e) {
                unsigned int p0 = edges[ee];
                const ushort4* x0 =
                    (const ushort4*)(Xb + ((size_t)(p0 >> 15) << 7));
                ushort4 q0 = x0[lane];
                float v0 = __uint_as_float((p0 & 0x7FFFu) << 16);
                a0.x += v0 * bf2f(q0.x); a0.y += v0 * bf2f(q0.y);
                a0.z += v0 * bf2f(q0.z); a0.w += v0 * bf2f(q0.w);
            }
            a0.x += a1.x; a0.y += a1.y; a0.z += a1.z; a0.w += a1.w;
            ((float4*)&sIn[ln][0])[lane] = a0;
        }
        __syncthreads();

        // ---- Phase B: GEMM1 (msg @ W1), relu + bfr, back into sIn
        float acc1[8][2];
#pragma unroll
        for (int rr = 0; rr < 8; ++rr) { acc1[rr][0] = 0.f; acc1[rr][1] = 0.f; }
        for (int k4 = 0; k4 < DIM / 4; ++k4) {
            float wa[4], wb[4];
#pragma unroll
            for (int j = 0; j < 4; ++j) {
                wa[j] = W1[(k4 * 4 + j) * DIM + l];
                wb[j] = W1[(k4 * 4 + j) * DIM + l + 64];
            }
#pragma unroll
            for (int rr = 0; rr < 8; ++rr) {
                float4 m = *(const float4*)&sIn[w * 8 + rr][k4 * 4];
                acc1[rr][0] += m.x * wa[0] + m.y * wa[1] + m.z * wa[2] + m.w * wa[3];
                acc1[rr][1] += m.x * wb[0] + m.y * wb[1] + m.z * wb[2] + m.w * wb[3];
            }
        }
        __syncthreads();   // all sIn reads done
        {
            float b0 = bfr[r * DIM + l], b1 = bfr[r * DIM + l + 64];
#pragma unroll
            for (int rr = 0; rr < 8; ++rr) {
                sIn[w * 8 + rr][l]      = fmaxf(acc1[rr][0] + b0, 0.f);
                sIn[w * 8 + rr][l + 64] = fmaxf(acc1[rr][1] + b1, 0.f);
            }
        }
        __syncthreads();

        // ---- Phase C: GEMM2 (@ W_rel[r]), weighted accumulate in regs
        const float* W2 = Wr + (size_t)r * DIM * DIM;
        float acc2[8][2];
#pragma unroll
        for (int rr = 0; rr < 8; ++rr) { acc2[rr][0] = 0.f; acc2[rr][1] = 0.f; }
        for (int k4 = 0; k4 < DIM / 4; ++k4) {
            float wa[4], wb[4];
#pragma unroll
            for (int j = 0; j < 4; ++j) {
                wa[j] = W2[(k4 * 4 + j) * DIM + l];
                wb[j] = W2[(k4 * 4 + j) * DIM + l + 64];
            }
#pragma unroll
            for (int rr = 0; rr < 8; ++rr) {
                float4 m = *(const float4*)&sIn[w * 8 + rr][k4 * 4];
                acc2[rr][0] += m.x * wa[0] + m.y * wa[1] + m.z * wa[2] + m.w * wa[3];
                acc2[rr][1] += m.x * wb[0] + m.y * wb[1] + m.z * wb[2] + m.w * wb[3];
            }
        }
        {
            float wr_ = wsm[r];
            float bb0 = br[r * DIM + l], bb1 = br[r * DIM + l + 64];
#pragma unroll
            for (int rr = 0; rr < 8; ++rr) {
                comb_acc[rr][0] += wr_ * (acc2[rr][0] + bb0);
                comb_acc[rr][1] += wr_ * (acc2[rr][1] + bb1);
            }
        }
        // top-of-loop barrier protects sIn before next gather
    }

    if (!do_final) {
#pragma unroll
        for (int rr = 0; rr < 8; ++rr) {
            size_t gi = (size_t)(row0 + w * 8 + rr) * DIM + l;
            comb[gi]      = comb_acc[rr][0];
            comb[gi + 64] = comb_acc[rr][1];
        }
        return;
    }

    // ---- Final: out = LN(X + sigmoid(X@Wg + bg) * comb)
    __syncthreads();
    {
        const float4* src = (const float4*)(X + (size_t)row0 * DIM);
        float4* dst = (float4*)&sIn[0][0];
        for (int i = t; i < 32 * DIM / 4; i += 256) dst[i] = src[i];
    }
    __syncthreads();

    float accg[8][2];
#pragma unroll
    for (int rr = 0; rr < 8; ++rr) { accg[rr][0] = 0.f; accg[rr][1] = 0.f; }
    for (int k4 = 0; k4 < DIM / 4; ++k4) {
        float wa[4], wb[4];
#pragma unroll
        for (int j = 0; j < 4; ++j) {
            wa[j] = Wg[(k4 * 4 + j) * DIM + l];
            wb[j] = Wg[(k4 * 4 + j) * DIM + l + 64];
        }
#pragma unroll
        for (int rr = 0; rr < 8; ++rr) {
            float4 m = *(const float4*)&sIn[w * 8 + rr][k4 * 4];
            accg[rr][0] += m.x * wa[0] + m.y * wa[1] + m.z * wa[2] + m.w * wa[3];
            accg[rr][1] += m.x * wb[0] + m.y * wb[1] + m.z * wb[2] + m.w * wb[3];
        }
    }
    float xv[8][2];
    {
        float bg0 = bg[l], bg1 = bg[l + 64];
#pragma unroll
        for (int rr = 0; rr < 8; ++rr) {
            int row = w * 8 + rr;
            float g0 = 1.f / (1.f + expf(-(accg[rr][0] + bg0)));
            float g1 = 1.f / (1.f + expf(-(accg[rr][1] + bg1)));
            xv[rr][0] = sIn[row][l]      + g0 * comb_acc[rr][0];
            xv[rr][1] = sIn[row][l + 64] + g1 * comb_acc[rr][1];
        }
    }
    __syncthreads();
#pragma unroll
    for (int rr = 0; rr < 8; ++rr) {
        sIn[w * 8 + rr][l]      = xv[rr][0];
        sIn[w * 8 + rr][l + 64] = xv[rr][1];
    }
    __syncthreads();

    {   // LN reduction: 8 threads per row x 16 cols each
        int row = t >> 3, seg = t & 7;
        float s = 0.f, s2 = 0.f;
#pragma unroll
        for (int i = 0; i < 16; ++i) {
            float v = sIn[row][seg * 16 + i];
            s += v; s2 += v * v;
        }
        red[row][seg] = s;
        red2[row][seg] = s2;
    }
    __syncthreads();
    if ((t & 7) == 0) {
        int row = t >> 3;
        float ts = 0.f, ts2 = 0.f;
#pragma unroll
        for (int i = 0; i < 8; ++i) { ts += red[row][i]; ts2 += red2[row][i]; }
        float mu = ts / DIM;
        float var = ts2 / DIM - mu * mu;
        smu[row] = mu;
        srs[row] = rsqrtf(var + LN_EPS);
    }
    __syncthreads();
    {
        float gm0 = gamma[l], gm1 = gamma[l + 64];
        float bt0 = beta[l],  bt1 = beta[l + 64];
#pragma unroll
        for (int rr = 0; rr < 8; ++rr) {
            int row = w * 8 + rr;
            size_t gi = (size_t)(row0 + row) * DIM + l;
            out[gi]      = (sIn[row][l]      - smu[row]) * srs[row] * gm0 + bt0;
            out[gi + 64] = (sIn[row][l + 64] - smu[row]) * srs[row] * gm1 + bt1;
        }
    }
}

// ---------------------------------------------------------------------------
extern "C" void kernel_launch(void* const* d_in, const int* in_sizes, int n_in,
                              void* d_out, int out_size, void* d_ws, size_t ws_size,
                              hipStream_t stream) {
    const float* X     = (const float*)d_in[0];
    const float* rel   = (const float*)d_in[1];
    const int*   arows = (const int*)d_in[2];
    const int*   acols = (const int*)d_in[3];
    const float* avals = (const float*)d_in[4];
    const float* Wf    = (const float*)d_in[5];
    const float* bf    = (const float*)d_in[6];
    const float* Wr    = (const float*)d_in[7];
    const float* br    = (const float*)d_in[8];
    const float* rw    = (const float*)d_in[9];
    const float* Wg    = (const float*)d_in[10];
    const float* bg    = (const float*)d_in[11];
    const float* gamma = (const float*)d_in[12];
    const float* beta  = (const float*)d_in[13];
    float* out = (float*)d_out;

    // pick relations-per-group by available workspace:
    // need(nr) = Xb 25.6MB + edges nr*6.4MB + counts nr*0.4MB + 4.2KB
    const size_t XB_B = (size_t)N_NODES * DIM * 2;
    size_t fixed = XB_B + 2048 * 2 + 64;
    int nr = 1;
    if (ws_size >= fixed + 4 * ((size_t)NEDGE * 4 + (size_t)N_NODES * 4)) nr = 4;
    else if (ws_size >= fixed + 2 * ((size_t)NEDGE * 4 + (size_t)N_NODES * 4)) nr = 2;

    unsigned short* Xb     = (unsigned short*)d_ws;
    unsigned int*   edges  = (unsigned int*)((char*)d_ws + XB_B);
    int*            counts = (int*)(edges + (size_t)nr * NEDGE);
    int*            chunks = counts + (size_t)nr * N_NODES;
    float*          bfr    = (float*)(chunks + 512);
    float*          wsm    = bfr + NREL * DIM;
    float*          comb   = out;   // accumulated in d_out; final pass is
                                    // block-local in-place

    prep_kernel<<<1, 512, 0, stream>>>(rel, Wf, bf, rw, bfr, wsm);
    xb_kernel<<<N_NODES * DIM / 4 / 256, 256, 0, stream>>>(X, Xb);

    const int EB = (NEDGE + 255) / 256;   // 6250
    for (int r0 = 0; r0 < NREL; r0 += nr) {
        int g = (NREL - r0 < nr) ? (NREL - r0) : nr;
        int M = g * N_NODES;
        int nch = (M + 1023) / 1024;
        hipMemsetAsync(counts, 0, (size_t)M * sizeof(int), stream);
        hist_kernel<<<dim3(EB, g), 256, 0, stream>>>(arows, r0, counts);
        scan1_kernel<<<nch, 256, 0, stream>>>(counts, chunks, M);
        scan2_kernel<<<1, 512, 0, stream>>>(chunks, nch);
        scan3_kernel<<<nch, 256, 0, stream>>>(counts, chunks, M);
        reorder_kernel<<<dim3(EB, g), 256, 0, stream>>>(
            arows, acols, avals, r0, counts, edges);
        mega_kernel<<<N_NODES / 32, 256, 0, stream>>>(
            Xb, X, counts, edges, Wf, bfr, Wr, br, wsm,
            r0, g, r0 > 0 ? 1 : 0, (r0 + g == NREL) ? 1 : 0,
            Wg, bg, gamma, beta, comb, out);
    }
}